// Round 6
// baseline (260.681 us; speedup 1.0000x reference)
//
#include <hip/hip_runtime.h>
#include <hip/hip_bf16.h>
#include <hip/hip_cooperative_groups.h>
#include <math.h>
#include <stdint.h>

namespace cg = cooperative_groups;

// ---------------------------------------------------------------------------
// attention_net (MI355X gfx950)
//   conv1: 2048->128 14x14 s1p1 | conv2: 128->128 ->7x7 s2p1 | conv3: ->4x4
//   All three convs: split-bf16 (hi+lo) MFMA 32x32x16, NHWC padded-16x16 A.
//   Then 1x1 heads -> scores(8,1614) -> greedy-NMS top6 -> bilinear crop.
// R6: cooperative mega-tail. 3 dispatches: prep, conv1 (R0-verbatim 41.5us),
//     then ONE cooperative kernel {red1,conv2,red2,conv3,red3,heads,nms,crop}
//     with grid.sync() between phases (each phase keeps full parallelism --
//     fixes R3's serial-reduce mistake). Occupancy-sized grid + legacy
//     fallback to the R5 10-dispatch sequence if coop launch unavailable.
// Output floats: part_imgs[7225344], coords[192], top_prob[48], top_idx[48]
// ---------------------------------------------------------------------------

#define OFF_COORDS 7225344
#define OFF_PROB   7225536
#define OFF_IDX    7225584
#define NA 1614
#define K1TOT 18432

typedef __attribute__((ext_vector_type(8)))  short  short8;
typedef __attribute__((ext_vector_type(16))) float  floatx16;

__device__ inline void split_bf16(float v, unsigned short& h, unsigned short& l)
{
    __hip_bfloat16 hb = __float2bfloat16(v);
    float hv = __bfloat162float(hb);
    __hip_bfloat16 lb = __float2bfloat16(v - hv);
    h = *reinterpret_cast<unsigned short*>(&hb);
    l = *reinterpret_cast<unsigned short*>(&lb);
}

// ---- unified prep: 3200 blocks ---------------------------------------------
__global__ __launch_bounds__(256) void k_prep(const float* __restrict__ rpn,
                                              const float* __restrict__ w1,
                                              const float* __restrict__ w2,
                                              const float* __restrict__ w3,
                                              unsigned short* __restrict__ ah,
                                              unsigned short* __restrict__ al,
                                              unsigned short* __restrict__ b1h,
                                              unsigned short* __restrict__ b1l,
                                              unsigned short* __restrict__ b2h,
                                              unsigned short* __restrict__ b2l,
                                              unsigned short* __restrict__ b3h,
                                              unsigned short* __restrict__ b3l)
{
    __shared__ float tileA[64][65];
    __shared__ float tileB[9][260];
    const int bid = blockIdx.x;
    const int t   = threadIdx.x;

    if (bid < 1024) {                     // ---- prep_a
        const int cib  = (bid & 31) * 64;
        const int posb = ((bid >> 5) & 3) * 64;
        const int b    = bid >> 7;
#pragma unroll
        for (int it = 0; it < 16; ++it) {
            int idx  = it * 256 + t;
            int cil  = idx >> 6;
            int posl = idx & 63;
            int pos  = posb + posl;
            int py = pos >> 4, px = pos & 15;
            int y = py - 1, x = px - 1;
            float v = 0.0f;
            if ((unsigned)y < 14u && (unsigned)x < 14u)
                v = rpn[((size_t)(b * 2048 + cib + cil) * 14 + y) * 14 + x];
            tileA[cil][posl] = v;
        }
        __syncthreads();
#pragma unroll
        for (int it = 0; it < 16; ++it) {
            int idx  = it * 256 + t;
            int posl = idx >> 6;
            int cil  = idx & 63;
            float v = tileA[cil][posl];
            unsigned short h, l;
            split_bf16(v, h, l);
            size_t o = (size_t)(b * 256 + posb + posl) * 2048 + cib + cil;
            ah[o] = h; al[o] = l;
        }
    } else if (bid < 2048) {              // ---- prep_b (conv1)
        const int lb  = bid - 1024;
        const int ci0 = (lb & 7) * 256;
        const int co  = lb >> 3;
        const float* wc = w1 + (size_t)co * K1TOT + (size_t)ci0 * 9;
#pragma unroll
        for (int it = 0; it < 9; ++it) {
            int i = it * 256 + t;
            float v = wc[i];
            tileB[i % 9][i / 9] = v;
        }
        __syncthreads();
#pragma unroll
        for (int tap = 0; tap < 9; ++tap) {
            float v = tileB[tap][t];
            unsigned short h, l;
            split_bf16(v, h, l);
            size_t o = (size_t)co * K1TOT + (size_t)tap * 2048 + ci0 + t;
            b1h[o] = h; b1l[o] = l;
        }
    } else {                              // ---- prep_w23
        const int lb  = bid - 2048;
        const int tap = lb % 9;
        const int co  = lb / 9;
        const int z   = t >> 7;
        const int ci  = t & 127;
        const float* w = z ? w3 : w2;
        unsigned short* bh = z ? b3h : b2h;
        unsigned short* bl = z ? b3l : b2l;
        float v = w[((size_t)co * 128 + ci) * 9 + tap];
        unsigned short h, l;
        split_bf16(v, h, l);
        size_t o = (size_t)co * 1152 + tap * 128 + ci;
        bh[o] = h; bl[o] = l;
    }
}

// ---- shared conv tile: 128m x 128n, 4 waves, K-stage 32 (R0 schedule) -----
template<int POSN, int OW, int STR, int CIN, int MTOT>
__device__ void conv_tile(const short* __restrict__ ah,
                          const short* __restrict__ al,
                          const short* __restrict__ bh,
                          const short* __restrict__ bl,
                          float* __restrict__ partial,
                          int mb, int kc, int chunk, char* smem)
{
    constexpr int KTOT = CIN * 9;
    short (*AsH)[40] = (short(*)[40])(smem);
    short (*AsL)[40] = (short(*)[40])(smem + 10240);
    short (*BsH)[40] = (short(*)[40])(smem + 20480);
    short (*BsL)[40] = (short(*)[40])(smem + 30720);

    const int t     = threadIdx.x;
    const int lane  = t & 63;
    const int w     = t >> 6;
    const int wm    = (w & 1) * 64;
    const int wn    = (w >> 1) * 64;
    const int lm    = lane & 31;
    const int half  = lane >> 5;
    const int mbase = mb * 128;
    const int k0    = kc * chunk;
    const int k1    = (k0 + chunk < KTOT) ? (k0 + chunk) : KTOT;

    int arow[2], apos[2]; bool aval[2];
    const int akc = (t & 3) * 8;
#pragma unroll
    for (int i = 0; i < 2; ++i) {
        int row = ((i * 256 + t) >> 2);
        int m   = mbase + row;
        arow[i] = row;
        aval[i] = (m < MTOT);
        int mm = aval[i] ? m : 0;
        int b  = mm / POSN;
        int p  = mm - b * POSN;
        int y  = p / OW;
        int x  = p - y * OW;
        apos[i] = b * 256 + y * STR * 16 + x * STR;
    }

    floatx16 acc[2][2];
#pragma unroll
    for (int mf = 0; mf < 2; ++mf)
#pragma unroll
        for (int nf = 0; nf < 2; ++nf)
#pragma unroll
            for (int r = 0; r < 16; ++r) acc[mf][nf][r] = 0.0f;

    const short8 zero8 = {0, 0, 0, 0, 0, 0, 0, 0};

    for (int ks = k0; ks < k1; ks += 32) {
        const int tap = ks / CIN;        // stage (32) never straddles a tap
        const int ci0 = ks - tap * CIN;
        const int dy  = tap / 3, dx = tap - dy * 3;
#pragma unroll
        for (int i = 0; i < 2; ++i) {
            short8 vh = zero8, vl = zero8;
            if (aval[i]) {
                size_t g = (size_t)(apos[i] + dy * 16 + dx) * CIN + ci0 + akc;
                vh = *(const short8*)(ah + g);
                vl = *(const short8*)(al + g);
            }
            *(short8*)&AsH[arow[i]][akc] = vh;
            *(short8*)&AsL[arow[i]][akc] = vl;
        }
#pragma unroll
        for (int i = 0; i < 2; ++i) {
            int n = ((i * 256 + t) >> 2);
            size_t g = (size_t)n * KTOT + ks + akc;
            *(short8*)&BsH[n][akc] = *(const short8*)(bh + g);
            *(short8*)&BsL[n][akc] = *(const short8*)(bl + g);
        }
        __syncthreads();
#pragma unroll
        for (int kst = 0; kst < 2; ++kst) {
            const int koff = kst * 16 + half * 8;
            short8 a_h[2], a_l[2], b_h[2], b_l[2];
#pragma unroll
            for (int mf = 0; mf < 2; ++mf) {
                a_h[mf] = *(const short8*)&AsH[wm + mf * 32 + lm][koff];
                a_l[mf] = *(const short8*)&AsL[wm + mf * 32 + lm][koff];
            }
#pragma unroll
            for (int nf = 0; nf < 2; ++nf) {
                b_h[nf] = *(const short8*)&BsH[wn + nf * 32 + lm][koff];
                b_l[nf] = *(const short8*)&BsL[wn + nf * 32 + lm][koff];
            }
#pragma unroll
            for (int mf = 0; mf < 2; ++mf)
#pragma unroll
                for (int nf = 0; nf < 2; ++nf) {
                    acc[mf][nf] = __builtin_amdgcn_mfma_f32_32x32x16_bf16(
                        a_h[mf], b_h[nf], acc[mf][nf], 0, 0, 0);
                    acc[mf][nf] = __builtin_amdgcn_mfma_f32_32x32x16_bf16(
                        a_h[mf], b_l[nf], acc[mf][nf], 0, 0, 0);
                    acc[mf][nf] = __builtin_amdgcn_mfma_f32_32x32x16_bf16(
                        a_l[mf], b_h[nf], acc[mf][nf], 0, 0, 0);
                }
        }
        __syncthreads();
    }

    float* P = partial + (size_t)kc * MTOT * 128;
#pragma unroll
    for (int mf = 0; mf < 2; ++mf)
#pragma unroll
        for (int nf = 0; nf < 2; ++nf)
#pragma unroll
            for (int r = 0; r < 16; ++r) {
                int row = (r & 3) + 8 * (r >> 2) + 4 * half;
                int m = mbase + wm + mf * 32 + row;
                int n = wn + nf * 32 + lm;
                if (m < MTOT) P[(size_t)m * 128 + n] = acc[mf][nf][r];
            }
}

// ---- device phase bodies ---------------------------------------------------
template<int POSN, int OWV>
__device__ void reduce_pad_slot(int idx, const float* __restrict__ partial,
                                const float* __restrict__ bias,
                                float* __restrict__ dn,
                                __hip_bfloat16* __restrict__ ph,
                                __hip_bfloat16* __restrict__ pl, int S)
{
    constexpr int MTOT = 8 * POSN;
    int b   = idx >> 13;
    int pos = (idx >> 5) & 255;
    int c4  = idx & 31;
    int y = (pos >> 4) - 1;
    int x = (pos & 15) - 1;
    if ((unsigned)y < (unsigned)OWV && (unsigned)x < (unsigned)OWV) {
        int m = b * POSN + y * OWV + x;
        float4 s = ((const float4*)bias)[c4];
        for (int k = 0; k < S; ++k) {
            float4 p = ((const float4*)(partial + (size_t)k * MTOT * 128 + (size_t)m * 128))[c4];
            s.x += p.x; s.y += p.y; s.z += p.z; s.w += p.w;
        }
        s.x = fmaxf(s.x, 0.0f); s.y = fmaxf(s.y, 0.0f);
        s.z = fmaxf(s.z, 0.0f); s.w = fmaxf(s.w, 0.0f);
        ((float4*)dn)[(size_t)m * 32 + c4] = s;
        ushort4 h, l;
        split_bf16(s.x, h.x, l.x);
        split_bf16(s.y, h.y, l.y);
        split_bf16(s.z, h.z, l.z);
        split_bf16(s.w, h.w, l.w);
        ((ushort4*)ph)[idx] = h;
        ((ushort4*)pl)[idx] = l;
    } else {
        ushort4 z = {0, 0, 0, 0};
        ((ushort4*)ph)[idx] = z;
        ((ushort4*)pl)[idx] = z;
    }
}

__device__ void reduce3_slot(int idx, const float* __restrict__ partial,
                             const float* __restrict__ bias,
                             float* __restrict__ dn, int S)
{
    int c4 = idx & 31;
    float4 s = ((const float4*)bias)[c4];
    for (int k = 0; k < S; ++k) {
        float4 p = ((const float4*)(partial + (size_t)k * 128 * 128))[idx];
        s.x += p.x; s.y += p.y; s.z += p.z; s.w += p.w;
    }
    s.x = fmaxf(s.x, 0.0f); s.y = fmaxf(s.y, 0.0f);
    s.z = fmaxf(s.z, 0.0f); s.w = fmaxf(s.w, 0.0f);
    ((float4*)dn)[idx] = s;
}

__device__ void heads_one(int idx,
                          const float* __restrict__ d1n,
                          const float* __restrict__ d2n,
                          const float* __restrict__ d3n,
                          const float* __restrict__ w1, const float* __restrict__ b1,
                          const float* __restrict__ w2, const float* __restrict__ b2,
                          const float* __restrict__ w3, const float* __restrict__ b3,
                          float* __restrict__ scores)
{
    if (idx >= 8 * NA) return;
    int b = idx / NA;
    int e = idx - b * NA;
    const float* d; const float* w; float bias;
    if (e < 1176) {
        int c = e / 196, p = e - c * 196;
        d = d1n + (size_t)(b * 196 + p) * 128; w = w1 + c * 128; bias = b1[c];
    } else if (e < 1470) {
        int e2 = e - 1176; int c = e2 / 49, p = e2 - c * 49;
        d = d2n + (size_t)(b * 49 + p) * 128; w = w2 + c * 128; bias = b2[c];
    } else {
        int e2 = e - 1470; int c = e2 / 16, p = e2 - c * 16;
        d = d3n + (size_t)(b * 16 + p) * 128; w = w3 + c * 128; bias = b3[c];
    }
    float s = bias;
#pragma unroll
    for (int i = 0; i < 32; ++i) {
        float4 dv = ((const float4*)d)[i];
        float4 wv = ((const float4*)w)[i];
        s = fmaf(dv.x, wv.x, s);
        s = fmaf(dv.y, wv.y, s);
        s = fmaf(dv.z, wv.z, s);
        s = fmaf(dv.w, wv.w, s);
    }
    scores[idx] = s;
}

__device__ void nms_block(int b, char* smem,
                          const float* __restrict__ scores,
                          const float* __restrict__ anchors,
                          float* __restrict__ out,
                          int* __restrict__ boxes)
{
    float* ms  = (float*)smem;
    float* ay0 = ms + NA;
    float* ax0 = ay0 + NA;
    float* ay1 = ax0 + NA;
    float* ax1 = ay1 + NA;
    unsigned char* picked = (unsigned char*)(ax1 + NA);
    float* rv  = (float*)(picked + ((NA + 15) & ~15));
    int*   ri  = (int*)(rv + 4);
    float* win = (float*)(ri + 4);
    int t = threadIdx.x;
    for (int i = t; i < NA; i += 256) {
        ms[i] = scores[b * NA + i];
        float4 an = ((const float4*)anchors)[i];
        ay0[i] = an.x; ax0[i] = an.y; ay1[i] = an.z; ax1[i] = an.w;
        picked[i] = 0;
    }
    __syncthreads();
    for (int r = 0; r < 6; ++r) {
        float bv = -INFINITY; int bi = NA;
        for (int i = t; i < NA; i += 256) {
            if (!picked[i]) {
                float v = ms[i];
                if (v > bv || (v == bv && i < bi)) { bv = v; bi = i; }
            }
        }
#pragma unroll
        for (int off = 32; off > 0; off >>= 1) {
            float v2 = __shfl_down(bv, off);
            int   i2 = __shfl_down(bi, off);
            if (v2 > bv || (v2 == bv && i2 < bi)) { bv = v2; bi = i2; }
        }
        if ((t & 63) == 0) { rv[t >> 6] = bv; ri[t >> 6] = bi; }
        __syncthreads();
        if (t == 0) {
            bv = rv[0]; bi = ri[0];
            for (int wv = 1; wv < 4; ++wv)
                if (rv[wv] > bv || (rv[wv] == bv && ri[wv] < bi)) { bv = rv[wv]; bi = ri[wv]; }
            picked[bi] = 1;
            win[0] = ay0[bi]; win[1] = ax0[bi]; win[2] = ay1[bi]; win[3] = ax1[bi];
            int o = b * 6 + r;
            out[OFF_COORDS + o * 4 + 0] = ax0[bi];
            out[OFF_COORDS + o * 4 + 1] = ay0[bi];
            out[OFF_COORDS + o * 4 + 2] = ax1[bi];
            out[OFF_COORDS + o * 4 + 3] = ay1[bi];
            out[OFF_PROB + o] = bv;
            out[OFF_IDX  + o] = (float)bi;
            boxes[o * 4 + 0] = (int)ax0[bi];
            boxes[o * 4 + 1] = (int)ay0[bi];
            boxes[o * 4 + 2] = (int)ax1[bi];
            boxes[o * 4 + 3] = (int)ay1[bi];
        }
        __syncthreads();
        float by0 = win[0], bx0 = win[1], by1 = win[2], bx1 = win[3];
        float barea = (by1 - by0) * (bx1 - bx0);
        for (int i = t; i < NA; i += 256) {
            if (picked[i]) continue;
            float ih = fmaxf(fminf(by1, ay1[i]) - fmaxf(by0, ay0[i]), 0.0f);
            float iw = fmaxf(fminf(bx1, ax1[i]) - fmaxf(bx0, ax0[i]), 0.0f);
            float inter = ih * iw;
            float area  = (ay1[i] - ay0[i]) * (ax1[i] - ax0[i]);
            float iou = inter / (barea + area - inter);
            if (iou > 0.25f) ms[i] = -INFINITY;
        }
        __syncthreads();
    }
}

__device__ void crop4_one(int idx, const float* __restrict__ x,
                          const int* __restrict__ boxes,
                          float* __restrict__ out)
{
    int qi  = idx % 56;
    int j   = (idx / 56) % 224;
    int rem = idx / (56 * 224);
    int c   = rem % 3;
    int br  = rem / 3;
    int b   = br / 6;
    int4 bx = ((const int4*)boxes)[br];
    float tj = (float)j / 223.0f;
    float sy = (float)bx.y + tj * (float)(bx.w - 1 - bx.y);
    int y0i = (int)floorf(sy);
    int y1i = min(y0i + 1, bx.w - 1);
    float wy = sy - (float)y0i;
    const float* img = x + ((size_t)b * 3 + c) * 448 * 448;
    auto g = [&](int yy, int xx) -> float {
        yy -= 224; xx -= 224;
        if ((unsigned)yy >= 448u || (unsigned)xx >= 448u) return 0.0f;
        return img[(size_t)yy * 448 + xx];
    };
    float4 o;
#pragma unroll
    for (int e = 0; e < 4; ++e) {
        int i = qi * 4 + e;
        float ti = (float)i / 223.0f;
        float sx = (float)bx.x + ti * (float)(bx.z - 1 - bx.x);
        int x0i = (int)floorf(sx);
        int x1i = min(x0i + 1, bx.z - 1);
        float wx = sx - (float)x0i;
        float g00 = g(y0i, x0i), g01 = g(y0i, x1i);
        float g10 = g(y1i, x0i), g11 = g(y1i, x1i);
        float top = (1.0f - wx) * g00 + wx * g01;
        float bot = (1.0f - wx) * g10 + wx * g11;
        float v = (1.0f - wy) * top + wy * bot;
        if (e == 0) o.x = v; else if (e == 1) o.y = v;
        else if (e == 2) o.z = v; else o.w = v;
    }
    ((float4*)out)[idx] = o;
}

// ---- standalone wrappers (conv1 + legacy fallback path) --------------------
template<int POSN, int OW, int STR, int CIN, int MTOT>
__global__ __launch_bounds__(256) void k_conv_mfma(const short* __restrict__ ah,
                                                   const short* __restrict__ al,
                                                   const short* __restrict__ bh,
                                                   const short* __restrict__ bl,
                                                   float* __restrict__ partial,
                                                   int chunk)
{
    __shared__ short8 smemv[2560];
    conv_tile<POSN, OW, STR, CIN, MTOT>(ah, al, bh, bl, partial,
                                        blockIdx.x, blockIdx.y, chunk, (char*)smemv);
}

template<int POSN, int OWV>
__global__ __launch_bounds__(256) void k_reduce_pad(const float* __restrict__ partial,
                                                    const float* __restrict__ bias,
                                                    float* __restrict__ dn,
                                                    __hip_bfloat16* __restrict__ ph,
                                                    __hip_bfloat16* __restrict__ pl,
                                                    int S)
{
    reduce_pad_slot<POSN, OWV>(blockIdx.x * 256 + threadIdx.x, partial, bias, dn, ph, pl, S);
}

__global__ __launch_bounds__(256) void k_reduce3(const float* __restrict__ partial,
                                                 const float* __restrict__ bias,
                                                 float* __restrict__ dn, int S)
{
    reduce3_slot(blockIdx.x * 256 + threadIdx.x, partial, bias, dn, S);
}

__global__ __launch_bounds__(256) void k_heads(const float* __restrict__ d1n,
                                               const float* __restrict__ d2n,
                                               const float* __restrict__ d3n,
                                               const float* __restrict__ w1, const float* __restrict__ b1,
                                               const float* __restrict__ w2, const float* __restrict__ b2,
                                               const float* __restrict__ w3, const float* __restrict__ b3,
                                               float* __restrict__ scores)
{
    heads_one(blockIdx.x * 256 + threadIdx.x, d1n, d2n, d3n, w1, b1, w2, b2, w3, b3, scores);
}

__global__ __launch_bounds__(256) void k_nms_topk(const float* __restrict__ scores,
                                                  const float* __restrict__ anchors,
                                                  float* __restrict__ out,
                                                  int* __restrict__ boxes)
{
    __shared__ short8 smemv[2560];
    nms_block(blockIdx.x, (char*)smemv, scores, anchors, out, boxes);
}

__global__ __launch_bounds__(256) void k_crop4(const float* __restrict__ x,
                                               const int* __restrict__ boxes,
                                               float* __restrict__ out)
{
    crop4_one(blockIdx.x * 256 + threadIdx.x, x, boxes, out);
}

// ---- cooperative mega-tail -------------------------------------------------
struct TailArgs {
    float *P1, *P2, *P3;
    const float *bd1, *bd2, *bd3;
    float *d1n, *d2n, *d3n;
    __hip_bfloat16 *d1ph, *d1pl, *d2ph, *d2pl;
    const short *b2h, *b2l, *b3h, *b3l;
    const float *hw1, *hb1, *hw2, *hb2, *hw3, *hb3;
    float *sc;
    const float *anch;
    float *out;
    int *boxes;
    const float *x;
    int S1;
};

__global__ __launch_bounds__(256, 4) void k_megatail(TailArgs a)
{
    __shared__ short8 smemv[2560];
    char* smem = (char*)smemv;
    cg::grid_group grid = cg::this_grid();
    const int t = threadIdx.x;
    const int gs = gridDim.x * 256;

    // P0: reduce conv1 partials -> d1n + padded d1ph/d1pl
    for (int idx = blockIdx.x * 256 + t; idx < 8 * 256 * 32; idx += gs)
        reduce_pad_slot<196, 14>(idx, a.P1, a.bd1, a.d1n, a.d1ph, a.d1pl, a.S1);
    grid.sync();
    // P1: conv2 (4 m-tiles x 36 k-chunks)
    for (int vb = blockIdx.x; vb < 144; vb += gridDim.x)
        conv_tile<49, 7, 2, 128, 392>((const short*)a.d1ph, (const short*)a.d1pl,
                                      a.b2h, a.b2l, a.P2, vb & 3, vb >> 2, 32, smem);
    grid.sync();
    // P2: reduce conv2 -> d2n + padded d2ph/d2pl
    for (int idx = blockIdx.x * 256 + t; idx < 8 * 256 * 32; idx += gs)
        reduce_pad_slot<49, 7>(idx, a.P2, a.bd2, a.d2n, a.d2ph, a.d2pl, 36);
    grid.sync();
    // P3: conv3 (1 m-tile x 36 k-chunks)
    for (int vb = blockIdx.x; vb < 36; vb += gridDim.x)
        conv_tile<16, 4, 2, 128, 128>((const short*)a.d2ph, (const short*)a.d2pl,
                                      a.b3h, a.b3l, a.P3, 0, vb, 32, smem);
    grid.sync();
    // P4: reduce conv3 -> d3n
    for (int idx = blockIdx.x * 256 + t; idx < 4096; idx += gs)
        reduce3_slot(idx, a.P3, a.bd3, a.d3n, 36);
    grid.sync();
    // P5: 1x1 heads -> scores
    for (int idx = blockIdx.x * 256 + t; idx < 8 * NA; idx += gs)
        heads_one(idx, a.d1n, a.d2n, a.d3n, a.hw1, a.hb1, a.hw2, a.hb2, a.hw3, a.hb3, a.sc);
    grid.sync();
    // P6: greedy NMS top-6 (8 independent batches)
    for (int vb = blockIdx.x; vb < 8; vb += gridDim.x)
        nms_block(vb, smem, a.sc, a.anch, a.out, a.boxes);
    grid.sync();
    // P7: bilinear crop
    for (int idx = blockIdx.x * 256 + t; idx < 48 * 3 * 224 * 56; idx += gs)
        crop4_one(idx, a.x, a.boxes, a.out);
}

// ---------------------------------------------------------------------------
extern "C" void kernel_launch(void* const* d_in, const int* in_sizes, int n_in,
                              void* d_out, int out_size, void* d_ws, size_t ws_size,
                              hipStream_t stream)
{
    (void)in_sizes; (void)n_in; (void)out_size;
    const float* x    = (const float*)d_in[0];
    const float* rpn  = (const float*)d_in[1];
    const float* anch = (const float*)d_in[2];
    const float* wd1  = (const float*)d_in[3];
    const float* bd1  = (const float*)d_in[4];
    const float* wd2  = (const float*)d_in[5];
    const float* bd2  = (const float*)d_in[6];
    const float* wd3  = (const float*)d_in[7];
    const float* bd3  = (const float*)d_in[8];
    const float* hw1  = (const float*)d_in[9];
    const float* hb1  = (const float*)d_in[10];
    const float* hw2  = (const float*)d_in[11];
    const float* hb2  = (const float*)d_in[12];
    const float* hw3  = (const float*)d_in[13];
    const float* hb3  = (const float*)d_in[14];
    float* out = (float*)d_out;

    char* ws = (char*)d_ws;
    size_t off = 0;
    auto alloc = [&](size_t bytes) -> void* {
        void* p = ws + off;
        off = (off + bytes + 255) & ~(size_t)255;
        return p;
    };
    unsigned short* ahb = (unsigned short*)alloc((size_t)8 * 256 * 2048 * 2);
    unsigned short* alb = (unsigned short*)alloc((size_t)8 * 256 * 2048 * 2);
    unsigned short* b1h = (unsigned short*)alloc((size_t)128 * K1TOT * 2);
    unsigned short* b1l = (unsigned short*)alloc((size_t)128 * K1TOT * 2);
    unsigned short* b2h = (unsigned short*)alloc((size_t)128 * 1152 * 2);
    unsigned short* b2l = (unsigned short*)alloc((size_t)128 * 1152 * 2);
    unsigned short* b3h = (unsigned short*)alloc((size_t)128 * 1152 * 2);
    unsigned short* b3l = (unsigned short*)alloc((size_t)128 * 1152 * 2);
    __hip_bfloat16* d1ph = (__hip_bfloat16*)alloc((size_t)8 * 256 * 128 * 2);
    __hip_bfloat16* d1pl = (__hip_bfloat16*)alloc((size_t)8 * 256 * 128 * 2);
    __hip_bfloat16* d2ph = (__hip_bfloat16*)alloc((size_t)8 * 256 * 128 * 2);
    __hip_bfloat16* d2pl = (__hip_bfloat16*)alloc((size_t)8 * 256 * 128 * 2);
    float* d1n  = (float*)alloc((size_t)8 * 196 * 128 * 4);
    float* d2n  = (float*)alloc((size_t)8 * 49 * 128 * 4);
    float* d3n  = (float*)alloc((size_t)8 * 16 * 128 * 4);
    float* sc   = (float*)alloc((size_t)8 * NA * 4);
    int*  boxes = (int*)alloc((size_t)8 * 6 * 4 * 4);
    float* P2   = (float*)alloc((size_t)36 * 392 * 128 * 4);
    float* P3   = (float*)alloc((size_t)36 * 128 * 128 * 4);
    size_t avail = (ws_size > off) ? (ws_size - off) : 0;
    float* P1 = (float*)(ws + off);

    long long s1 = (long long)(avail / ((size_t)1568 * 128 * 4));
    if (s1 > 48) s1 = 48;
    if (s1 < 1)  s1 = 1;
    int S1 = (int)s1;
    int chunk1 = ((K1TOT + S1 * 32 - 1) / (S1 * 32)) * 32;

    // 1) unified prep
    k_prep<<<dim3(3200), 256, 0, stream>>>(rpn, wd1, wd2, wd3,
        ahb, alb, b1h, b1l, b2h, b2l, b3h, b3l);

    // 2) conv1: M=1568, CIN=2048 (R0 schedule), grid 13 x S1
    k_conv_mfma<196, 14, 1, 2048, 1568><<<dim3(13, S1), 256, 0, stream>>>(
        (const short*)ahb, (const short*)alb, (const short*)b1h, (const short*)b1l, P1, chunk1);

    // 3) cooperative mega-tail (red1..crop) -- fallback to legacy on failure
    static int coopBlocks = -1;
    if (coopBlocks < 0) {
        int maxB = 0;
        hipError_t e = hipOccupancyMaxActiveBlocksPerMultiprocessor(
            &maxB, reinterpret_cast<const void*>(k_megatail), 256, 0);
        if (e == hipSuccess && maxB > 0) {
            int nCU = 256;
            hipDeviceProp_t prop;
            if (hipGetDeviceProperties(&prop, 0) == hipSuccess && prop.multiProcessorCount > 0)
                nCU = prop.multiProcessorCount;
            if (maxB > 4) maxB = 4;
            coopBlocks = maxB * nCU;
        } else {
            coopBlocks = 0;
        }
    }

    bool legacy = true;
    if (coopBlocks >= 256) {
        TailArgs ta;
        ta.P1 = P1; ta.P2 = P2; ta.P3 = P3;
        ta.bd1 = bd1; ta.bd2 = bd2; ta.bd3 = bd3;
        ta.d1n = d1n; ta.d2n = d2n; ta.d3n = d3n;
        ta.d1ph = d1ph; ta.d1pl = d1pl; ta.d2ph = d2ph; ta.d2pl = d2pl;
        ta.b2h = (const short*)b2h; ta.b2l = (const short*)b2l;
        ta.b3h = (const short*)b3h; ta.b3l = (const short*)b3l;
        ta.hw1 = hw1; ta.hb1 = hb1; ta.hw2 = hw2; ta.hb2 = hb2; ta.hw3 = hw3; ta.hb3 = hb3;
        ta.sc = sc; ta.anch = anch; ta.out = out; ta.boxes = boxes; ta.x = x;
        ta.S1 = S1;
        void* args[] = { &ta };
        hipError_t e = hipLaunchCooperativeKernel(
            reinterpret_cast<const void*>(k_megatail),
            dim3(coopBlocks), dim3(256), args, 0, stream);
        if (e == hipSuccess) legacy = false;
        else coopBlocks = 0;          // don't retry next calls
    }

    if (legacy) {
        k_reduce_pad<196, 14><<<dim3(256), 256, 0, stream>>>(P1, bd1, d1n, d1ph, d1pl, S1);
        k_conv_mfma<49, 7, 2, 128, 392><<<dim3(4, 36), 256, 0, stream>>>(
            (const short*)d1ph, (const short*)d1pl, (const short*)b2h, (const short*)b2l, P2, 32);
        k_reduce_pad<49, 7><<<dim3(256), 256, 0, stream>>>(P2, bd2, d2n, d2ph, d2pl, 36);
        k_conv_mfma<16, 4, 2, 128, 128><<<dim3(1, 36), 256, 0, stream>>>(
            (const short*)d2ph, (const short*)d2pl, (const short*)b3h, (const short*)b3l, P3, 32);
        k_reduce3<<<dim3(16), 256, 0, stream>>>(P3, bd3, d3n, 36);
        k_heads<<<dim3((8 * NA + 255) / 256), 256, 0, stream>>>(d1n, d2n, d3n,
            hw1, hb1, hw2, hb2, hw3, hb3, sc);
        k_nms_topk<<<dim3(8), 256, 0, stream>>>(sc, anch, out, boxes);
        k_crop4<<<dim3(7056), 256, 0, stream>>>(x, boxes, out);
    }
}

// Round 7
// 251.652 us; speedup vs baseline: 1.0359x; 1.0359x over previous
//
#include <hip/hip_runtime.h>
#include <hip/hip_bf16.h>
#include <math.h>
#include <stdint.h>

// ---------------------------------------------------------------------------
// attention_net (MI355X gfx950)
//   conv1: 2048->128 14x14 s1p1 | conv2: 128->128 ->7x7 s2p1 | conv3: ->4x4
//   All three convs: split-bf16 (hi+lo) MFMA 32x32x16, NHWC padded-16x16 A.
//   Then 1x1 heads -> scores(8,1614) -> greedy-NMS top6 -> bilinear crop.
// R7: R5 structure (best: 253.7us) with k_heads FUSED into the reduce
//     kernels (block-local fusion: a reduce block owns 8 full 128-ch
//     vectors -> compute the 6/9 head dots in-block via LDS). 9 dispatches.
//     R6 lesson: grid.sync ~36us on MI355X -- never trade launches for it.
// Output floats: part_imgs[7225344], coords[192], top_prob[48], top_idx[48]
// ---------------------------------------------------------------------------

#define OFF_COORDS 7225344
#define OFF_PROB   7225536
#define OFF_IDX    7225584
#define NA 1614
#define K1TOT 18432

typedef __attribute__((ext_vector_type(8)))  short  short8;
typedef __attribute__((ext_vector_type(16))) float  floatx16;

__device__ inline void split_bf16(float v, unsigned short& h, unsigned short& l)
{
    __hip_bfloat16 hb = __float2bfloat16(v);
    float hv = __bfloat162float(hb);
    __hip_bfloat16 lb = __float2bfloat16(v - hv);
    h = *reinterpret_cast<unsigned short*>(&hb);
    l = *reinterpret_cast<unsigned short*>(&lb);
}

// ---- unified prep: 3200 blocks ---------------------------------------------
__global__ __launch_bounds__(256) void k_prep(const float* __restrict__ rpn,
                                              const float* __restrict__ w1,
                                              const float* __restrict__ w2,
                                              const float* __restrict__ w3,
                                              unsigned short* __restrict__ ah,
                                              unsigned short* __restrict__ al,
                                              unsigned short* __restrict__ b1h,
                                              unsigned short* __restrict__ b1l,
                                              unsigned short* __restrict__ b2h,
                                              unsigned short* __restrict__ b2l,
                                              unsigned short* __restrict__ b3h,
                                              unsigned short* __restrict__ b3l)
{
    __shared__ float tileA[64][65];
    __shared__ float tileB[9][260];
    const int bid = blockIdx.x;
    const int t   = threadIdx.x;

    if (bid < 1024) {                     // ---- prep_a
        const int cib  = (bid & 31) * 64;
        const int posb = ((bid >> 5) & 3) * 64;
        const int b    = bid >> 7;
#pragma unroll
        for (int it = 0; it < 16; ++it) {
            int idx  = it * 256 + t;
            int cil  = idx >> 6;
            int posl = idx & 63;
            int pos  = posb + posl;
            int py = pos >> 4, px = pos & 15;
            int y = py - 1, x = px - 1;
            float v = 0.0f;
            if ((unsigned)y < 14u && (unsigned)x < 14u)
                v = rpn[((size_t)(b * 2048 + cib + cil) * 14 + y) * 14 + x];
            tileA[cil][posl] = v;
        }
        __syncthreads();
#pragma unroll
        for (int it = 0; it < 16; ++it) {
            int idx  = it * 256 + t;
            int posl = idx >> 6;
            int cil  = idx & 63;
            float v = tileA[cil][posl];
            unsigned short h, l;
            split_bf16(v, h, l);
            size_t o = (size_t)(b * 256 + posb + posl) * 2048 + cib + cil;
            ah[o] = h; al[o] = l;
        }
    } else if (bid < 2048) {              // ---- prep_b (conv1)
        const int lb  = bid - 1024;
        const int ci0 = (lb & 7) * 256;
        const int co  = lb >> 3;
        const float* wc = w1 + (size_t)co * K1TOT + (size_t)ci0 * 9;
#pragma unroll
        for (int it = 0; it < 9; ++it) {
            int i = it * 256 + t;
            float v = wc[i];
            tileB[i % 9][i / 9] = v;
        }
        __syncthreads();
#pragma unroll
        for (int tap = 0; tap < 9; ++tap) {
            float v = tileB[tap][t];
            unsigned short h, l;
            split_bf16(v, h, l);
            size_t o = (size_t)co * K1TOT + (size_t)tap * 2048 + ci0 + t;
            b1h[o] = h; b1l[o] = l;
        }
    } else {                              // ---- prep_w23
        const int lb  = bid - 2048;
        const int tap = lb % 9;
        const int co  = lb / 9;
        const int z   = t >> 7;
        const int ci  = t & 127;
        const float* w = z ? w3 : w2;
        unsigned short* bh = z ? b3h : b2h;
        unsigned short* bl = z ? b3l : b2l;
        float v = w[((size_t)co * 128 + ci) * 9 + tap];
        unsigned short h, l;
        split_bf16(v, h, l);
        size_t o = (size_t)co * 1152 + tap * 128 + ci;
        bh[o] = h; bl[o] = l;
    }
}

// ---- conv1: R0-verbatim split-bf16 MFMA implicit-GEMM ---------------------
template<int POSN, int OW, int STR, int CIN, int MTOT>
__global__ __launch_bounds__(256) void k_conv_mfma(const short* __restrict__ ah,
                                                   const short* __restrict__ al,
                                                   const short* __restrict__ bh,
                                                   const short* __restrict__ bl,
                                                   float* __restrict__ partial,
                                                   int chunk)
{
    constexpr int KTOT = CIN * 9;
    __shared__ short AsH[128][40];
    __shared__ short AsL[128][40];
    __shared__ short BsH[128][40];
    __shared__ short BsL[128][40];

    const int t     = threadIdx.x;
    const int lane  = t & 63;
    const int w     = t >> 6;
    const int wm    = (w & 1) * 64;
    const int wn    = (w >> 1) * 64;
    const int lm    = lane & 31;
    const int half  = lane >> 5;
    const int mbase = blockIdx.x * 128;
    const int k0    = blockIdx.y * chunk;
    const int k1    = (k0 + chunk < KTOT) ? (k0 + chunk) : KTOT;

    int arow[2], apos[2]; bool aval[2];
    const int akc = (t & 3) * 8;
#pragma unroll
    for (int i = 0; i < 2; ++i) {
        int row = ((i * 256 + t) >> 2);
        int m   = mbase + row;
        arow[i] = row;
        aval[i] = (m < MTOT);
        int mm = aval[i] ? m : 0;
        int b  = mm / POSN;
        int p  = mm - b * POSN;
        int y  = p / OW;
        int x  = p - y * OW;
        apos[i] = b * 256 + y * STR * 16 + x * STR;
    }

    floatx16 acc[2][2];
#pragma unroll
    for (int mf = 0; mf < 2; ++mf)
#pragma unroll
        for (int nf = 0; nf < 2; ++nf)
#pragma unroll
            for (int r = 0; r < 16; ++r) acc[mf][nf][r] = 0.0f;

    const short8 zero8 = {0, 0, 0, 0, 0, 0, 0, 0};

    for (int ks = k0; ks < k1; ks += 32) {
        const int tap = ks / CIN;        // stage (32) never straddles a tap
        const int ci0 = ks - tap * CIN;
        const int dy  = tap / 3, dx = tap - dy * 3;
#pragma unroll
        for (int i = 0; i < 2; ++i) {
            short8 vh = zero8, vl = zero8;
            if (aval[i]) {
                size_t g = (size_t)(apos[i] + dy * 16 + dx) * CIN + ci0 + akc;
                vh = *(const short8*)(ah + g);
                vl = *(const short8*)(al + g);
            }
            *(short8*)&AsH[arow[i]][akc] = vh;
            *(short8*)&AsL[arow[i]][akc] = vl;
        }
#pragma unroll
        for (int i = 0; i < 2; ++i) {
            int n = ((i * 256 + t) >> 2);
            size_t g = (size_t)n * KTOT + ks + akc;
            *(short8*)&BsH[n][akc] = *(const short8*)(bh + g);
            *(short8*)&BsL[n][akc] = *(const short8*)(bl + g);
        }
        __syncthreads();
#pragma unroll
        for (int kst = 0; kst < 2; ++kst) {
            const int koff = kst * 16 + half * 8;
            short8 a_h[2], a_l[2], b_h[2], b_l[2];
#pragma unroll
            for (int mf = 0; mf < 2; ++mf) {
                a_h[mf] = *(const short8*)&AsH[wm + mf * 32 + lm][koff];
                a_l[mf] = *(const short8*)&AsL[wm + mf * 32 + lm][koff];
            }
#pragma unroll
            for (int nf = 0; nf < 2; ++nf) {
                b_h[nf] = *(const short8*)&BsH[wn + nf * 32 + lm][koff];
                b_l[nf] = *(const short8*)&BsL[wn + nf * 32 + lm][koff];
            }
#pragma unroll
            for (int mf = 0; mf < 2; ++mf)
#pragma unroll
                for (int nf = 0; nf < 2; ++nf) {
                    acc[mf][nf] = __builtin_amdgcn_mfma_f32_32x32x16_bf16(
                        a_h[mf], b_h[nf], acc[mf][nf], 0, 0, 0);
                    acc[mf][nf] = __builtin_amdgcn_mfma_f32_32x32x16_bf16(
                        a_h[mf], b_l[nf], acc[mf][nf], 0, 0, 0);
                    acc[mf][nf] = __builtin_amdgcn_mfma_f32_32x32x16_bf16(
                        a_l[mf], b_h[nf], acc[mf][nf], 0, 0, 0);
                }
        }
        __syncthreads();
    }

    float* P = partial + (size_t)blockIdx.y * MTOT * 128;
#pragma unroll
    for (int mf = 0; mf < 2; ++mf)
#pragma unroll
        for (int nf = 0; nf < 2; ++nf)
#pragma unroll
            for (int r = 0; r < 16; ++r) {
                int row = (r & 3) + 8 * (r >> 2) + 4 * half;
                int m = mbase + wm + mf * 32 + row;
                int n = wn + nf * 32 + lm;
                if (m < MTOT) P[(size_t)m * 128 + n] = acc[mf][nf][r];
            }
}

// ---- conv2/3: 64-row m-tile, 2 waves, 128 threads (R4, 1 iter/block) ------
template<int POSN, int OW, int STR, int CIN, int MTOT>
__global__ __launch_bounds__(128) void k_conv64(const short* __restrict__ ah,
                                                const short* __restrict__ al,
                                                const short* __restrict__ bh,
                                                const short* __restrict__ bl,
                                                float* __restrict__ partial,
                                                int chunk)
{
    constexpr int KTOT = CIN * 9;
    __shared__ short AsH[64][40];
    __shared__ short AsL[64][40];
    __shared__ short BsH[128][40];
    __shared__ short BsL[128][40];

    const int t     = threadIdx.x;
    const int lane  = t & 63;
    const int w     = t >> 6;            // 0..1
    const int wn    = w * 64;
    const int lm    = lane & 31;
    const int half  = lane >> 5;
    const int mbase = blockIdx.x * 64;
    const int kc    = blockIdx.y;
    const int k0    = kc * chunk;
    const int k1    = (k0 + chunk < KTOT) ? (k0 + chunk) : KTOT;

    const int akc = (t & 3) * 8;
    int arow[2], apos[2]; bool aval[2];
#pragma unroll
    for (int i = 0; i < 2; ++i) {
        int slot = i * 128 + t;
        int row  = slot >> 2;            // 0..63
        int m    = mbase + row;
        arow[i] = row;
        aval[i] = (m < MTOT);
        int mm = aval[i] ? m : 0;
        int b  = mm / POSN;
        int p  = mm - b * POSN;
        int y  = p / OW;
        int x  = p - y * OW;
        apos[i] = b * 256 + y * STR * 16 + x * STR;
    }

    floatx16 acc[2][2];
#pragma unroll
    for (int mf = 0; mf < 2; ++mf)
#pragma unroll
        for (int nf = 0; nf < 2; ++nf)
#pragma unroll
            for (int r = 0; r < 16; ++r) acc[mf][nf][r] = 0.0f;

    const short8 zero8 = {0, 0, 0, 0, 0, 0, 0, 0};

    for (int ks = k0; ks < k1; ks += 32) {
        const int tap = ks / CIN;
        const int ci0 = ks - tap * CIN;
        const int dy  = tap / 3, dx = tap - dy * 3;
#pragma unroll
        for (int i = 0; i < 2; ++i) {
            short8 vh = zero8, vl = zero8;
            if (aval[i]) {
                size_t g = (size_t)(apos[i] + dy * 16 + dx) * CIN + ci0 + akc;
                vh = *(const short8*)(ah + g);
                vl = *(const short8*)(al + g);
            }
            *(short8*)&AsH[arow[i]][akc] = vh;
            *(short8*)&AsL[arow[i]][akc] = vl;
        }
#pragma unroll
        for (int j = 0; j < 4; ++j) {
            int n = ((j * 128 + t) >> 2);    // 0..127
            size_t g = (size_t)n * KTOT + ks + akc;
            *(short8*)&BsH[n][akc] = *(const short8*)(bh + g);
            *(short8*)&BsL[n][akc] = *(const short8*)(bl + g);
        }
        __syncthreads();
#pragma unroll
        for (int kst = 0; kst < 2; ++kst) {
            const int koff = kst * 16 + half * 8;
            short8 a_h[2], a_l[2], b_h[2], b_l[2];
#pragma unroll
            for (int mf = 0; mf < 2; ++mf) {
                a_h[mf] = *(const short8*)&AsH[mf * 32 + lm][koff];
                a_l[mf] = *(const short8*)&AsL[mf * 32 + lm][koff];
            }
#pragma unroll
            for (int nf = 0; nf < 2; ++nf) {
                b_h[nf] = *(const short8*)&BsH[wn + nf * 32 + lm][koff];
                b_l[nf] = *(const short8*)&BsL[wn + nf * 32 + lm][koff];
            }
#pragma unroll
            for (int mf = 0; mf < 2; ++mf)
#pragma unroll
                for (int nf = 0; nf < 2; ++nf) {
                    acc[mf][nf] = __builtin_amdgcn_mfma_f32_32x32x16_bf16(
                        a_h[mf], b_h[nf], acc[mf][nf], 0, 0, 0);
                    acc[mf][nf] = __builtin_amdgcn_mfma_f32_32x32x16_bf16(
                        a_h[mf], b_l[nf], acc[mf][nf], 0, 0, 0);
                    acc[mf][nf] = __builtin_amdgcn_mfma_f32_32x32x16_bf16(
                        a_l[mf], b_h[nf], acc[mf][nf], 0, 0, 0);
                }
        }
        __syncthreads();
    }

    float* P = partial + (size_t)kc * MTOT * 128;
#pragma unroll
    for (int mf = 0; mf < 2; ++mf)
#pragma unroll
        for (int nf = 0; nf < 2; ++nf)
#pragma unroll
            for (int r = 0; r < 16; ++r) {
                int row = (r & 3) + 8 * (r >> 2) + 4 * half;
                int m = mbase + mf * 32 + row;
                int n = wn + nf * 32 + lm;
                if (m < MTOT) P[(size_t)m * 128 + n] = acc[mf][nf][r];
            }
}

// ---- fused reduce + heads: partials -> dn/bf16-pads AND per-position scores
// Block = 256 threads = 8 padded positions x 32 c4 chunks of one batch.
// After the reduce, the block holds the full 128-ch vectors of its 8
// positions -> stage in LDS, compute NH head dots per valid position.
template<int POSN, int OWV, int NH, int SBASE>
__global__ __launch_bounds__(256) void k_reduce_heads(const float* __restrict__ partial,
                                                      const float* __restrict__ bias,
                                                      float* __restrict__ dn,
                                                      __hip_bfloat16* __restrict__ ph,
                                                      __hip_bfloat16* __restrict__ pl,
                                                      const float* __restrict__ hw,
                                                      const float* __restrict__ hb,
                                                      float* __restrict__ scores,
                                                      int S)
{
    constexpr int MTOT = 8 * POSN;
    __shared__ float dtile[8][132];
    int idx = blockIdx.x * 256 + threadIdx.x;   // < 8*256*32
    int t   = threadIdx.x;
    int b   = idx >> 13;
    int pos = (idx >> 5) & 255;
    int c4  = idx & 31;
    int y = (pos >> 4) - 1;
    int x = (pos & 15) - 1;
    bool valid = ((unsigned)y < (unsigned)OWV) && ((unsigned)x < (unsigned)OWV);
    if (valid) {
        int m = b * POSN + y * OWV + x;
        float4 s = ((const float4*)bias)[c4];
        for (int k = 0; k < S; ++k) {
            float4 p = ((const float4*)(partial + (size_t)k * MTOT * 128 + (size_t)m * 128))[c4];
            s.x += p.x; s.y += p.y; s.z += p.z; s.w += p.w;
        }
        s.x = fmaxf(s.x, 0.0f); s.y = fmaxf(s.y, 0.0f);
        s.z = fmaxf(s.z, 0.0f); s.w = fmaxf(s.w, 0.0f);
        ((float4*)dn)[(size_t)m * 32 + c4] = s;
        ushort4 h, l;
        split_bf16(s.x, h.x, l.x);
        split_bf16(s.y, h.y, l.y);
        split_bf16(s.z, h.z, l.z);
        split_bf16(s.w, h.w, l.w);
        ((ushort4*)ph)[idx] = h;
        ((ushort4*)pl)[idx] = l;
        dtile[t >> 5][c4 * 4 + 0] = s.x;
        dtile[t >> 5][c4 * 4 + 1] = s.y;
        dtile[t >> 5][c4 * 4 + 2] = s.z;
        dtile[t >> 5][c4 * 4 + 3] = s.w;
    } else {
        ushort4 z = {0, 0, 0, 0};
        ((ushort4*)ph)[idx] = z;
        ((ushort4*)pl)[idx] = z;
    }
    __syncthreads();
    if (t < 8 * NH) {
        int pl_ = t / NH;
        int c   = t - pl_ * NH;
        int i0  = blockIdx.x * 256 + pl_ * 32;
        int bb  = i0 >> 13;
        int pp  = (i0 >> 5) & 255;
        int yy  = (pp >> 4) - 1;
        int xx  = (pp & 15) - 1;
        if ((unsigned)yy < (unsigned)OWV && (unsigned)xx < (unsigned)OWV) {
            float s = hb[c];
            const float* wv = hw + c * 128;
#pragma unroll 32
            for (int k = 0; k < 128; ++k)
                s = fmaf(dtile[pl_][k], wv[k], s);
            scores[bb * NA + SBASE + c * POSN + yy * OWV + xx] = s;
        }
    }
}

// ---- reduce conv3 + t3 heads -> d3n + scores ------------------------------
__global__ __launch_bounds__(256) void k_reduce3_heads(const float* __restrict__ partial,
                                                       const float* __restrict__ bias,
                                                       float* __restrict__ dn,
                                                       const float* __restrict__ hw,
                                                       const float* __restrict__ hb,
                                                       float* __restrict__ scores,
                                                       int S)
{
    __shared__ float dtile[8][132];
    int idx = blockIdx.x * 256 + threadIdx.x;   // < 4096 float4 slots
    int t   = threadIdx.x;
    int c4  = idx & 31;
    float4 s = ((const float4*)bias)[c4];
    for (int k = 0; k < S; ++k) {
        float4 p = ((const float4*)(partial + (size_t)k * 128 * 128))[idx];
        s.x += p.x; s.y += p.y; s.z += p.z; s.w += p.w;
    }
    s.x = fmaxf(s.x, 0.0f); s.y = fmaxf(s.y, 0.0f);
    s.z = fmaxf(s.z, 0.0f); s.w = fmaxf(s.w, 0.0f);
    ((float4*)dn)[idx] = s;
    dtile[t >> 5][c4 * 4 + 0] = s.x;
    dtile[t >> 5][c4 * 4 + 1] = s.y;
    dtile[t >> 5][c4 * 4 + 2] = s.z;
    dtile[t >> 5][c4 * 4 + 3] = s.w;
    __syncthreads();
    if (t < 8 * 9) {
        int pl_ = t / 9;
        int c   = t - pl_ * 9;
        int m   = (blockIdx.x * 256 + pl_ * 32) >> 5;   // global m slot
        int bb  = m >> 4;
        int pp  = m & 15;
        float sc = hb[c];
        const float* wv = hw + c * 128;
#pragma unroll 32
        for (int k = 0; k < 128; ++k)
            sc = fmaf(dtile[pl_][k], wv[k], sc);
        scores[bb * NA + 1470 + c * 16 + pp] = sc;
    }
}

// ---- NMS + top-6 (greedy NMS truncated at 6 == 6x argmax+suppress) --------
__global__ __launch_bounds__(256) void k_nms_topk(const float* __restrict__ scores,
                                                  const float* __restrict__ anchors,
                                                  float* __restrict__ out,
                                                  int* __restrict__ boxes)
{
    __shared__ float ms[NA];
    __shared__ float ay0[NA], ax0[NA], ay1[NA], ax1[NA];
    __shared__ unsigned char picked[NA];
    __shared__ float rv[4]; __shared__ int ri[4];
    __shared__ float win[5];
    int b = blockIdx.x;
    int t = threadIdx.x;
    for (int i = t; i < NA; i += 256) {
        ms[i] = scores[b * NA + i];
        float4 an = ((const float4*)anchors)[i];
        ay0[i] = an.x; ax0[i] = an.y; ay1[i] = an.z; ax1[i] = an.w;
        picked[i] = 0;
    }
    __syncthreads();
    for (int r = 0; r < 6; ++r) {
        float bv = -INFINITY; int bi = NA;
        for (int i = t; i < NA; i += 256) {
            if (!picked[i]) {
                float v = ms[i];
                if (v > bv || (v == bv && i < bi)) { bv = v; bi = i; }
            }
        }
#pragma unroll
        for (int off = 32; off > 0; off >>= 1) {
            float v2 = __shfl_down(bv, off);
            int   i2 = __shfl_down(bi, off);
            if (v2 > bv || (v2 == bv && i2 < bi)) { bv = v2; bi = i2; }
        }
        if ((t & 63) == 0) { rv[t >> 6] = bv; ri[t >> 6] = bi; }
        __syncthreads();
        if (t == 0) {
            bv = rv[0]; bi = ri[0];
            for (int wv = 1; wv < 4; ++wv)
                if (rv[wv] > bv || (rv[wv] == bv && ri[wv] < bi)) { bv = rv[wv]; bi = ri[wv]; }
            picked[bi] = 1;
            win[0] = ay0[bi]; win[1] = ax0[bi]; win[2] = ay1[bi]; win[3] = ax1[bi];
            int o = b * 6 + r;
            out[OFF_COORDS + o * 4 + 0] = ax0[bi];
            out[OFF_COORDS + o * 4 + 1] = ay0[bi];
            out[OFF_COORDS + o * 4 + 2] = ax1[bi];
            out[OFF_COORDS + o * 4 + 3] = ay1[bi];
            out[OFF_PROB + o] = bv;
            out[OFF_IDX  + o] = (float)bi;
            boxes[o * 4 + 0] = (int)ax0[bi];
            boxes[o * 4 + 1] = (int)ay0[bi];
            boxes[o * 4 + 2] = (int)ax1[bi];
            boxes[o * 4 + 3] = (int)ay1[bi];
        }
        __syncthreads();
        float by0 = win[0], bx0 = win[1], by1 = win[2], bx1 = win[3];
        float barea = (by1 - by0) * (bx1 - bx0);
        for (int i = t; i < NA; i += 256) {
            if (picked[i]) continue;
            float ih = fmaxf(fminf(by1, ay1[i]) - fmaxf(by0, ay0[i]), 0.0f);
            float iw = fmaxf(fminf(bx1, ax1[i]) - fmaxf(bx0, ax0[i]), 0.0f);
            float inter = ih * iw;
            float area  = (ay1[i] - ay0[i]) * (ax1[i] - ax0[i]);
            float iou = inter / (barea + area - inter);
            if (iou > 0.25f) ms[i] = -INFINITY;
        }
        __syncthreads();
    }
}

// ---- bilinear crop-resize: 4 consecutive x-outputs per thread, float4 store
__global__ __launch_bounds__(256) void k_crop4(const float* __restrict__ x,
                                               const int* __restrict__ boxes,
                                               float* __restrict__ out)
{
    int idx = blockIdx.x * 256 + threadIdx.x;   // < 48*3*224*56
    int qi  = idx % 56;
    int j   = (idx / 56) % 224;
    int rem = idx / (56 * 224);
    int c   = rem % 3;
    int br  = rem / 3;
    int b   = br / 6;
    int4 bx = ((const int4*)boxes)[br];
    float tj = (float)j / 223.0f;
    float sy = (float)bx.y + tj * (float)(bx.w - 1 - bx.y);
    int y0i = (int)floorf(sy);
    int y1i = min(y0i + 1, bx.w - 1);
    float wy = sy - (float)y0i;
    const float* img = x + ((size_t)b * 3 + c) * 448 * 448;
    auto g = [&](int yy, int xx) -> float {
        yy -= 224; xx -= 224;
        if ((unsigned)yy >= 448u || (unsigned)xx >= 448u) return 0.0f;
        return img[(size_t)yy * 448 + xx];
    };
    float4 o;
#pragma unroll
    for (int e = 0; e < 4; ++e) {
        int i = qi * 4 + e;
        float ti = (float)i / 223.0f;
        float sx = (float)bx.x + ti * (float)(bx.z - 1 - bx.x);
        int x0i = (int)floorf(sx);
        int x1i = min(x0i + 1, bx.z - 1);
        float wx = sx - (float)x0i;
        float g00 = g(y0i, x0i), g01 = g(y0i, x1i);
        float g10 = g(y1i, x0i), g11 = g(y1i, x1i);
        float top = (1.0f - wx) * g00 + wx * g01;
        float bot = (1.0f - wx) * g10 + wx * g11;
        float v = (1.0f - wy) * top + wy * bot;
        if (e == 0) o.x = v; else if (e == 1) o.y = v;
        else if (e == 2) o.z = v; else o.w = v;
    }
    ((float4*)out)[idx] = o;
}

// ---------------------------------------------------------------------------
extern "C" void kernel_launch(void* const* d_in, const int* in_sizes, int n_in,
                              void* d_out, int out_size, void* d_ws, size_t ws_size,
                              hipStream_t stream)
{
    (void)in_sizes; (void)n_in; (void)out_size;
    const float* x    = (const float*)d_in[0];
    const float* rpn  = (const float*)d_in[1];
    const float* anch = (const float*)d_in[2];
    const float* wd1  = (const float*)d_in[3];
    const float* bd1  = (const float*)d_in[4];
    const float* wd2  = (const float*)d_in[5];
    const float* bd2  = (const float*)d_in[6];
    const float* wd3  = (const float*)d_in[7];
    const float* bd3  = (const float*)d_in[8];
    const float* hw1  = (const float*)d_in[9];
    const float* hb1  = (const float*)d_in[10];
    const float* hw2  = (const float*)d_in[11];
    const float* hb2  = (const float*)d_in[12];
    const float* hw3  = (const float*)d_in[13];
    const float* hb3  = (const float*)d_in[14];
    float* out = (float*)d_out;

    char* ws = (char*)d_ws;
    size_t off = 0;
    auto alloc = [&](size_t bytes) -> void* {
        void* p = ws + off;
        off = (off + bytes + 255) & ~(size_t)255;
        return p;
    };
    unsigned short* ahb = (unsigned short*)alloc((size_t)8 * 256 * 2048 * 2);
    unsigned short* alb = (unsigned short*)alloc((size_t)8 * 256 * 2048 * 2);
    unsigned short* b1h = (unsigned short*)alloc((size_t)128 * K1TOT * 2);
    unsigned short* b1l = (unsigned short*)alloc((size_t)128 * K1TOT * 2);
    unsigned short* b2h = (unsigned short*)alloc((size_t)128 * 1152 * 2);
    unsigned short* b2l = (unsigned short*)alloc((size_t)128 * 1152 * 2);
    unsigned short* b3h = (unsigned short*)alloc((size_t)128 * 1152 * 2);
    unsigned short* b3l = (unsigned short*)alloc((size_t)128 * 1152 * 2);
    __hip_bfloat16* d1ph = (__hip_bfloat16*)alloc((size_t)8 * 256 * 128 * 2);
    __hip_bfloat16* d1pl = (__hip_bfloat16*)alloc((size_t)8 * 256 * 128 * 2);
    __hip_bfloat16* d2ph = (__hip_bfloat16*)alloc((size_t)8 * 256 * 128 * 2);
    __hip_bfloat16* d2pl = (__hip_bfloat16*)alloc((size_t)8 * 256 * 128 * 2);
    float* d1n  = (float*)alloc((size_t)8 * 196 * 128 * 4);
    float* d2n  = (float*)alloc((size_t)8 * 49 * 128 * 4);
    float* d3n  = (float*)alloc((size_t)8 * 16 * 128 * 4);
    float* sc   = (float*)alloc((size_t)8 * NA * 4);
    int*  boxes = (int*)alloc((size_t)8 * 6 * 4 * 4);
    size_t avail = (ws_size > off) ? (ws_size - off) : 0;
    float* P = (float*)(ws + off);

    long long s1 = (long long)(avail / ((size_t)1568 * 128 * 4));
    if (s1 > 48) s1 = 48;
    if (s1 < 1)  s1 = 1;
    int S1 = (int)s1;
    int chunk1 = ((K1TOT + S1 * 32 - 1) / (S1 * 32)) * 32;

    // 1) unified prep (weights + conv1 input)
    k_prep<<<dim3(3200), 256, 0, stream>>>(rpn, wd1, wd2, wd3,
        ahb, alb, b1h, b1l, b2h, b2l, b3h, b3l);

    // 2) conv1: M=1568, CIN=2048, 128-row tiles (R0 verbatim), grid 13 x S1
    k_conv_mfma<196, 14, 1, 2048, 1568><<<dim3(13, S1), 256, 0, stream>>>(
        (const short*)ahb, (const short*)alb, (const short*)b1h, (const short*)b1l, P, chunk1);

    // 3) reduce conv1 + t1 head scores
    k_reduce_heads<196, 14, 6, 0><<<dim3(256), 256, 0, stream>>>(
        P, bd1, d1n, d1ph, d1pl, hw1, hb1, sc, S1);

    // 4) conv2: M=392, CIN=128, K=1152, 64-row tiles, grid 7 x 36 (1 iter)
    k_conv64<49, 7, 2, 128, 392><<<dim3(7, 36), 128, 0, stream>>>(
        (const short*)d1ph, (const short*)d1pl, (const short*)b2h, (const short*)b2l, P, 32);

    // 5) reduce conv2 + t2 head scores
    k_reduce_heads<49, 7, 6, 1176><<<dim3(256), 256, 0, stream>>>(
        P, bd2, d2n, d2ph, d2pl, hw2, hb2, sc, 36);

    // 6) conv3: M=128, CIN=128, K=1152, 64-row tiles, grid 2 x 36 (1 iter)
    k_conv64<16, 4, 2, 128, 128><<<dim3(2, 36), 128, 0, stream>>>(
        (const short*)d2ph, (const short*)d2pl, (const short*)b3h, (const short*)b3l, P, 32);

    // 7) reduce conv3 + t3 head scores
    k_reduce3_heads<<<dim3(16), 256, 0, stream>>>(P, bd3, d3n, hw3, hb3, sc, 36);

    // 8) NMS + top-6 (LDS-only, 8 blocks)
    k_nms_topk<<<dim3(8), 256, 0, stream>>>(sc, anch, out, boxes);

    // 9) bilinear crop, 4 px/thread, float4 stores
    k_crop4<<<dim3(7056), 256, 0, stream>>>(x, boxes, out);
}